// Round 10
// baseline (197.316 us; speedup 1.0000x reference)
//
#include <hip/hip_runtime.h>
#include <math.h>

// Problem geometry (fixed by setup_inputs)
#define BB   256   // batch
#define DIN  2048  // layer-0 input dim
#define HH   512   // hidden dim
#define NSL  32    // i-slice split -> grid (HH/8, NSL) = 2048 blocks = 8/CU

#define NEG_HALF_LOG2E (-0.72134752044448170368f)
#define LOG2E           1.44269504088896340736f
#define LN2             0.69314718055994530942f

typedef float v2f __attribute__((ext_vector_type(2)));

__device__ __forceinline__ float fexp2(float x) { return __builtin_amdgcn_exp2f(x); }
__device__ __forceinline__ float silu_f(float y)
{
    return y * __builtin_amdgcn_rcpf(1.f + fexp2(-y * LOG2E));
}

// ---------------------------------------------------------------------------
// tz: transpose x [BB][DIN] -> x4 [DIN/4][BB] and zero acc.  grid 512 x 256.
// ---------------------------------------------------------------------------
__global__ __launch_bounds__(256) void tz_k(
    const float* __restrict__ in, float4* __restrict__ out4, float* __restrict__ acc)
{
    __shared__ float tile[32][33];
    int bid = blockIdx.x, t = threadIdx.x;
    acc[bid * 256 + t] = 0.0f;                 // 512*256 == HH*BB exactly
    int ct = bid & 63, rt = bid >> 6;          // 64 c-tiles x 8 r-tiles
    int c0 = ct * 32, r0 = rt * 32;
    int tx = t & 31, ty = t >> 5;              // (32, 8)
#pragma unroll
    for (int k = 0; k < 4; k++)
        tile[ty + 8*k][tx] = in[(size_t)(r0 + ty + 8*k) * DIN + c0 + tx];
    __syncthreads();
    float4 v = make_float4(tile[tx][4*ty + 0], tile[tx][4*ty + 1],
                           tile[tx][4*ty + 2], tile[tx][4*ty + 3]);
    out4[(size_t)(c0/4 + ty) * BB + (r0 + tx)] = v;
}

// ---------------------------------------------------------------------------
// wavelet kernel: 8 o-rows per block, in-block LDS param pack, x prefetch.
// P layout per g-iter: [rr][24] = { r[o0..7], t*r[o0..7], w[o0..7] }
// x4: [D/4][BB] float4; acc: [HH][BB] (atomic accumulate)
// ---------------------------------------------------------------------------
#define WAV_RR8(PB, RRBASE, XSC) {                                \
    float4 RA = *(const float4*)((PB) + (RRBASE));                \
    float4 RB = *(const float4*)((PB) + (RRBASE) + 4);            \
    float4 TA = *(const float4*)((PB) + (RRBASE) + 8);            \
    float4 TB = *(const float4*)((PB) + (RRBASE) + 12);           \
    float4 WA = *(const float4*)((PB) + (RRBASE) + 16);           \
    float4 WB = *(const float4*)((PB) + (RRBASE) + 20);           \
    v2f xx = {(XSC), (XSC)};                                      \
    { v2f R01 = {RA.x, RA.y}, R23 = {RA.z, RA.w};                 \
      v2f T01 = {TA.x, TA.y}, T23 = {TA.z, TA.w};                 \
      v2f W01 = {WA.x, WA.y}, W23 = {WA.z, WA.w};                 \
      v2f d01 = __builtin_elementwise_fma(xx, R01, -T01);         \
      v2f d23 = __builtin_elementwise_fma(xx, R23, -T23);         \
      v2f u01 = d01 * d01,  u23 = d23 * d23;                      \
      v2f g01 = u01 * k2,   g23 = u23 * k2;                       \
      v2f e01, e23;                                               \
      e01.x = fexp2(g01.x); e01.y = fexp2(g01.y);                 \
      e23.x = fexp2(g23.x); e23.y = fexp2(g23.y);                 \
      v2f p01 = __builtin_elementwise_fma(-W01, u01, W01);        \
      v2f p23 = __builtin_elementwise_fma(-W23, u23, W23);        \
      aA01 = __builtin_elementwise_fma(p01, e01, aA01);           \
      aA23 = __builtin_elementwise_fma(p23, e23, aA23); }         \
    { v2f R01 = {RB.x, RB.y}, R23 = {RB.z, RB.w};                 \
      v2f T01 = {TB.x, TB.y}, T23 = {TB.z, TB.w};                 \
      v2f W01 = {WB.x, WB.y}, W23 = {WB.z, WB.w};                 \
      v2f d01 = __builtin_elementwise_fma(xx, R01, -T01);         \
      v2f d23 = __builtin_elementwise_fma(xx, R23, -T23);         \
      v2f u01 = d01 * d01,  u23 = d23 * d23;                      \
      v2f g01 = u01 * k2,   g23 = u23 * k2;                       \
      v2f e01, e23;                                               \
      e01.x = fexp2(g01.x); e01.y = fexp2(g01.y);                 \
      e23.x = fexp2(g23.x); e23.y = fexp2(g23.y);                 \
      v2f p01 = __builtin_elementwise_fma(-W01, u01, W01);        \
      v2f p23 = __builtin_elementwise_fma(-W23, u23, W23);        \
      aB01 = __builtin_elementwise_fma(p01, e01, aB01);           \
      aB23 = __builtin_elementwise_fma(p23, e23, aB23); } }

template<int D>
__global__ __launch_bounds__(256, 8) void wav_k(
    const float4* __restrict__ x4,
    const float*  __restrict__ ss,
    const float*  __restrict__ tt,
    const float*  __restrict__ ww,
    float* __restrict__ acc)
{
    constexpr int G     = (D / 4) / NSL;   // g-iters: 16 (L0) or 4 (L1/2)
    constexpr int SLICE = G * 4;           // i's per slice: 64 or 16

    __shared__ float P[G * 96];

    const int q  = blockIdx.x;             // o-octet
    const int sl = blockIdx.y;             // i-slice
    const int t  = threadIdx.x;

    // ---- self-pack param slice into LDS: 8 o's x SLICE i's ----
    for (int e = t; e < 8 * SLICE; e += 256) {
        int oo = e / SLICE;                // 0..7
        int ii = e - oo * SLICE;
        size_t idx = (size_t)(q * 8 + oo) * D + (size_t)sl * SLICE + ii;
        float v  = ss[idx];
        float e2 = fexp2(-fabsf(v) * LOG2E);
        float sp = fmaxf(v, 0.0f) + LN2 * __builtin_amdgcn_logf(1.0f + e2);
        float rv = __builtin_amdgcn_rcpf(0.001f + sp + 1e-8f);
        int g = ii >> 2, rr = ii & 3;
        P[g * 96 + rr * 24 + 0  + oo] = rv;
        P[g * 96 + rr * 24 + 8  + oo] = tt[idx] * rv;
        P[g * 96 + rr * 24 + 16 + oo] = ww[idx];
    }
    __syncthreads();

    // ---- wavelet loop with 1-deep x prefetch ----
    const float4* xp = x4 + (size_t)sl * G * BB + t;
    v2f aA01 = {0.f, 0.f}, aA23 = {0.f, 0.f};
    v2f aB01 = {0.f, 0.f}, aB23 = {0.f, 0.f};
    const v2f k2 = {NEG_HALF_LOG2E, NEG_HALF_LOG2E};

    float4 xcur = xp[0];
#pragma unroll 2
    for (int g = 0; g < G; ++g) {
        float4 xnext = (g + 1 < G) ? xp[(size_t)(g + 1) * BB] : xcur;
        const float* pb = &P[g * 96];
        WAV_RR8(pb,  0, xcur.x)
        WAV_RR8(pb, 24, xcur.y)
        WAV_RR8(pb, 48, xcur.z)
        WAV_RR8(pb, 72, xcur.w)
        xcur = xnext;
    }

    float* dst = acc + (size_t)(8 * q) * BB + t;
    unsafeAtomicAdd(dst,        aA01.x);
    unsafeAtomicAdd(dst + BB,   aA01.y);
    unsafeAtomicAdd(dst + 2*BB, aA23.x);
    unsafeAtomicAdd(dst + 3*BB, aA23.y);
    unsafeAtomicAdd(dst + 4*BB, aB01.x);
    unsafeAtomicAdd(dst + 5*BB, aB01.y);
    unsafeAtomicAdd(dst + 6*BB, aB23.x);
    unsafeAtomicAdd(dst + 7*BB, aB23.y);
}

// ---------------------------------------------------------------------------
// finish: SiLU + layernorm for batch b; re-zeroes acc column.
// grid BB x 256 threads (t<128 active; all threads reach the barrier).
// ---------------------------------------------------------------------------
__global__ __launch_bounds__(256) void fin_k(
    float* __restrict__ acc, const float* __restrict__ g,
    const float* __restrict__ be, float4* __restrict__ fout4)
{
    __shared__ float ls[4];
    const int b = blockIdx.x, t = threadIdx.x;
    float v0 = 0.f, v1 = 0.f, v2 = 0.f, v3 = 0.f;
    if (t < 128) {
        float* ap = acc + (size_t)(4 * t) * BB + b;
        float y0 = ap[0], y1 = ap[BB], y2 = ap[2*BB], y3 = ap[3*BB];
        ap[0] = 0.f; ap[BB] = 0.f; ap[2*BB] = 0.f; ap[3*BB] = 0.f;
        v0 = silu_f(y0); v1 = silu_f(y1); v2 = silu_f(y2); v3 = silu_f(y3);
        float sum = v0 + v1 + v2 + v3;
        float ss  = v0*v0 + v1*v1 + v2*v2 + v3*v3;
#pragma unroll
        for (int off = 32; off; off >>= 1) {
            sum += __shfl_xor(sum, off);
            ss  += __shfl_xor(ss,  off);
        }
        int wid = t >> 6;
        if ((t & 63) == 0) { ls[wid] = sum; ls[2 + wid] = ss; }
    }
    __syncthreads();
    if (t < 128) {
        float sum = ls[0] + ls[1], ss = ls[2] + ls[3];
        float m   = sum * (1.0f / HH);
        float var = ss  * (1.0f / HH) - m * m;
        float rs  = rsqrtf(var + 1e-5f);
        float4 gv = ((const float4*)g)[t];
        float4 bv = ((const float4*)be)[t];
        fout4[(size_t)t * BB + b] = make_float4(gv.x * (v0 - m) * rs + bv.x,
                                                gv.y * (v1 - m) * rs + bv.y,
                                                gv.z * (v2 - m) * rs + bv.z,
                                                gv.w * (v3 - m) * rs + bv.w);
    }
}

// ---------------------------------------------------------------------------
// finish + classifier (layer 2): out[b][c] = sum_o f[o]*cw[c][o] + cb[c]
// ---------------------------------------------------------------------------
__global__ __launch_bounds__(256) void fcls_k(
    const float* __restrict__ acc, const float* __restrict__ g,
    const float* __restrict__ be, const float* __restrict__ cw,
    const float* __restrict__ cb, float* __restrict__ out)
{
    __shared__ float ls[4];
    const int b = blockIdx.x, t = threadIdx.x;
    float v0 = 0.f, v1 = 0.f, v2 = 0.f, v3 = 0.f;
    if (t < 128) {
        const float* ap = acc + (size_t)(4 * t) * BB + b;
        v0 = silu_f(ap[0]); v1 = silu_f(ap[BB]); v2 = silu_f(ap[2*BB]); v3 = silu_f(ap[3*BB]);
        float sum = v0 + v1 + v2 + v3;
        float ss  = v0*v0 + v1*v1 + v2*v2 + v3*v3;
#pragma unroll
        for (int off = 32; off; off >>= 1) {
            sum += __shfl_xor(sum, off);
            ss  += __shfl_xor(ss,  off);
        }
        int wid = t >> 6;
        if ((t & 63) == 0) { ls[wid] = sum; ls[2 + wid] = ss; }
    }
    __syncthreads();
    float c0 = 0.f, c1 = 0.f;
    if (t < 128) {
        float sum = ls[0] + ls[1], ss = ls[2] + ls[3];
        float m  = sum * (1.0f / HH);
        float var = ss * (1.0f / HH) - m * m;
        float rs = rsqrtf(var + 1e-5f);
        float f0 = g[4*t+0] * (v0 - m) * rs + be[4*t+0];
        float f1 = g[4*t+1] * (v1 - m) * rs + be[4*t+1];
        float f2 = g[4*t+2] * (v2 - m) * rs + be[4*t+2];
        float f3 = g[4*t+3] * (v3 - m) * rs + be[4*t+3];
        float4 ca  = ((const float4*)cw)[t];
        float4 cbv = ((const float4*)cw)[HH/4 + t];
        c0 = f0*ca.x  + f1*ca.y  + f2*ca.z  + f3*ca.w;
        c1 = f0*cbv.x + f1*cbv.y + f2*cbv.z + f3*cbv.w;
#pragma unroll
        for (int off = 32; off; off >>= 1) {
            c0 += __shfl_xor(c0, off);
            c1 += __shfl_xor(c1, off);
        }
    }
    __syncthreads();
    if (t < 128 && (t & 63) == 0) { int wid = t >> 6; ls[wid] = c0; ls[2 + wid] = c1; }
    __syncthreads();
    if (t == 0) {
        out[b * 2 + 0] = ls[0] + ls[1] + cb[0];
        out[b * 2 + 1] = ls[2] + ls[3] + cb[1];
    }
}

// ---------------------------------------------------------------------------
extern "C" void kernel_launch(void* const* d_in, const int* in_sizes, int n_in,
                              void* d_out, int out_size, void* d_ws, size_t ws_size,
                              hipStream_t stream)
{
    const float* x  = (const float*)d_in[0];
    const float* t0 = (const float*)d_in[1];
    const float* s0 = (const float*)d_in[2];
    const float* w0 = (const float*)d_in[3];
    const float* g0 = (const float*)d_in[4];
    const float* b0 = (const float*)d_in[5];
    const float* t1 = (const float*)d_in[6];
    const float* s1 = (const float*)d_in[7];
    const float* w1 = (const float*)d_in[8];
    const float* g1 = (const float*)d_in[9];
    const float* b1 = (const float*)d_in[10];
    const float* t2 = (const float*)d_in[11];
    const float* s2 = (const float*)d_in[12];
    const float* w2 = (const float*)d_in[13];
    const float* g2 = (const float*)d_in[14];
    const float* b2 = (const float*)d_in[15];
    const float* cw = (const float*)d_in[16];
    const float* cb = (const float*)d_in[17];
    float* out = (float*)d_out;

    float* ws = (float*)d_ws;
    // workspace (floats): x4 524288 + acc 131072 + fA 131072 = 786,432 fl = 3.1 MB
    float4* x4  = (float4*)ws;                          // [DIN/4][BB]
    float*  acc = ws + (size_t)(DIN/4) * BB * 4;        // [HH][BB]
    float4* fA  = (float4*)(acc + (size_t)HH * BB);     // [HH/4][BB]
    float4* fB  = x4;                                   // reuse x4 (dead after wav0)

    tz_k<<<512, 256, 0, stream>>>(x, x4, acc);

    // ---- layer 0: DIN -> HH ----
    wav_k<DIN><<<dim3(HH/8, NSL), 256, 0, stream>>>(x4, s0, t0, w0, acc);
    fin_k<<<BB, 256, 0, stream>>>(acc, g0, b0, fA);

    // ---- layer 1: HH -> HH ----
    wav_k<HH><<<dim3(HH/8, NSL), 256, 0, stream>>>((const float4*)fA, s1, t1, w1, acc);
    fin_k<<<BB, 256, 0, stream>>>(acc, g1, b1, fB);

    // ---- layer 2: HH -> HH + classifier ----
    wav_k<HH><<<dim3(HH/8, NSL), 256, 0, stream>>>((const float4*)fB, s2, t2, w2, acc);
    fcls_k<<<BB, 256, 0, stream>>>(acc, g2, b2, cw, cb, out);
}